// Round 1
// baseline (1698.813 us; speedup 1.0000x reference)
//
#include <hip/hip_runtime.h>
#include <hip/hip_bf16.h>
#include <math.h>

#define N_NODES 100000
#define DIM 128
#define HID 512
#define EDGES 600000

// ---------------------------------------------------------------------------
// Kernel 1: scatter-add  h[src] into accum[dst], count deg[dst]
// 256 threads = 8 edges x 32 lanes; each lane handles one float4 (4 dims)
// ---------------------------------------------------------------------------
__global__ __launch_bounds__(256) void mgl_scatter_kernel(
    const float* __restrict__ h, const int* __restrict__ ei,
    float* __restrict__ accum, float* __restrict__ deg)
{
    int lane = threadIdx.x & 31;
    int eloc = threadIdx.x >> 5;
    int e = blockIdx.x * 8 + eloc;
    if (e >= EDGES) return;
    int s = ei[e];          // src
    int t = ei[EDGES + e];  // dst
    float4 v = ((const float4*)(h + (size_t)s * DIM))[lane];
    float* ac = accum + (size_t)t * DIM + lane * 4;
    atomicAdd(ac + 0, v.x);
    atomicAdd(ac + 1, v.y);
    atomicAdd(ac + 2, v.z);
    atomicAdd(ac + 3, v.w);
    if (lane == 0) atomicAdd(deg + t, 1.0f);
}

// ---------------------------------------------------------------------------
// Kernel 2: hdn = gelu( [h, agg] @ W1 + b1 )   (agg computed on the fly)
// BM=64, BN=128, BK=64, 256 threads (16x16), 4x8 micro-tile per thread
// ---------------------------------------------------------------------------
__global__ __launch_bounds__(256) void mgl_mlp1_kernel(
    const float* __restrict__ h, const float* __restrict__ accum,
    const float* __restrict__ deg, const float* __restrict__ W1,
    const float* __restrict__ b1, float* __restrict__ hdn)
{
    __shared__ float XsT[64][68];   // [k][m]  transposed A tile
    __shared__ float Ws[64][132];   // [k][n]

    int tid = threadIdx.x;
    int ty = tid >> 4;   // 0..15
    int tx = tid & 15;   // 0..15
    int m0 = blockIdx.x * 64;
    int n0 = blockIdx.y * 128;

    float acc[4][8];
    #pragma unroll
    for (int i = 0; i < 4; ++i)
        #pragma unroll
        for (int j = 0; j < 8; ++j) acc[i][j] = 0.f;

    for (int kt = 0; kt < 4; ++kt) {
        // ---- load X tile (64 nodes x 64 k), computed on the fly ----
        {
            int r = tid >> 4;   // node row group
            int c = tid & 15;   // float4 index along k
            int kg = kt * 64 + c * 4;
            #pragma unroll
            for (int it = 0; it < 4; ++it) {
                int row = r + 16 * it;
                int node = m0 + row;
                int nc = node < N_NODES ? node : N_NODES - 1;
                float4 v;
                if (kg < DIM) {
                    v = *(const float4*)(h + (size_t)nc * DIM + kg);
                } else {
                    int kk = kg - DIM;
                    float d = deg[nc];
                    if (d > 0.f) {
                        float4 a = *(const float4*)(accum + (size_t)nc * DIM + kk);
                        float inv = 1.f / d;
                        v = make_float4(a.x * inv, a.y * inv, a.z * inv, a.w * inv);
                    } else {
                        v = *(const float4*)(h + (size_t)nc * DIM + kk);
                    }
                }
                XsT[c * 4 + 0][row] = v.x;
                XsT[c * 4 + 1][row] = v.y;
                XsT[c * 4 + 2][row] = v.z;
                XsT[c * 4 + 3][row] = v.w;
            }
        }
        // ---- load W1 tile (64 k x 128 n) ----
        {
            int kr = tid >> 5;   // 0..7
            int c4 = tid & 31;   // float4 col
            #pragma unroll
            for (int it = 0; it < 8; ++it) {
                int k = kr + 8 * it;
                float4 w = *(const float4*)(W1 + (size_t)(kt * 64 + k) * HID + n0 + c4 * 4);
                *(float4*)&Ws[k][c4 * 4] = w;
            }
        }
        __syncthreads();
        #pragma unroll
        for (int k = 0; k < 64; ++k) {
            float4 a4 = *(const float4*)&XsT[k][ty * 4];
            float4 b0 = *(const float4*)&Ws[k][tx * 4];
            float4 b1v = *(const float4*)&Ws[k][64 + tx * 4];
            float av[4] = {a4.x, a4.y, a4.z, a4.w};
            float bv[8] = {b0.x, b0.y, b0.z, b0.w, b1v.x, b1v.y, b1v.z, b1v.w};
            #pragma unroll
            for (int i = 0; i < 4; ++i)
                #pragma unroll
                for (int j = 0; j < 8; ++j)
                    acc[i][j] += av[i] * bv[j];
        }
        __syncthreads();
    }

    // ---- epilogue: bias + exact GELU, store hdn ----
    #pragma unroll
    for (int i = 0; i < 4; ++i) {
        int node = m0 + ty * 4 + i;
        if (node >= N_NODES) continue;
        #pragma unroll
        for (int j = 0; j < 8; ++j) {
            int col = (j < 4) ? (tx * 4 + j) : (64 + tx * 4 + (j - 4));
            float x = acc[i][j] + b1[n0 + col];
            float g = 0.5f * x * (1.0f + erff(x * 0.70710678118654752f));
            hdn[(size_t)node * HID + n0 + col] = g;
        }
    }
}

// ---------------------------------------------------------------------------
// Kernel 3: out = hdn @ W2 + b2
// BM=64, BN=128 (full DIM), BK=64, K=512
// ---------------------------------------------------------------------------
__global__ __launch_bounds__(256) void mgl_mlp2_kernel(
    const float* __restrict__ hdn, const float* __restrict__ W2,
    const float* __restrict__ b2, float* __restrict__ out)
{
    __shared__ float AsT[64][68];
    __shared__ float Ws[64][132];

    int tid = threadIdx.x;
    int ty = tid >> 4;
    int tx = tid & 15;
    int m0 = blockIdx.x * 64;

    float acc[4][8];
    #pragma unroll
    for (int i = 0; i < 4; ++i)
        #pragma unroll
        for (int j = 0; j < 8; ++j) acc[i][j] = 0.f;

    for (int kt = 0; kt < 8; ++kt) {
        {
            int r = tid >> 4;
            int c = tid & 15;
            #pragma unroll
            for (int it = 0; it < 4; ++it) {
                int row = r + 16 * it;
                int node = m0 + row;
                int nc = node < N_NODES ? node : N_NODES - 1;
                float4 v = *(const float4*)(hdn + (size_t)nc * HID + kt * 64 + c * 4);
                AsT[c * 4 + 0][row] = v.x;
                AsT[c * 4 + 1][row] = v.y;
                AsT[c * 4 + 2][row] = v.z;
                AsT[c * 4 + 3][row] = v.w;
            }
        }
        {
            int kr = tid >> 5;
            int c4 = tid & 31;
            #pragma unroll
            for (int it = 0; it < 8; ++it) {
                int k = kr + 8 * it;
                float4 w = *(const float4*)(W2 + (size_t)(kt * 64 + k) * DIM + c4 * 4);
                *(float4*)&Ws[k][c4 * 4] = w;
            }
        }
        __syncthreads();
        #pragma unroll
        for (int k = 0; k < 64; ++k) {
            float4 a4 = *(const float4*)&AsT[k][ty * 4];
            float4 b0 = *(const float4*)&Ws[k][tx * 4];
            float4 b1v = *(const float4*)&Ws[k][64 + tx * 4];
            float av[4] = {a4.x, a4.y, a4.z, a4.w};
            float bv[8] = {b0.x, b0.y, b0.z, b0.w, b1v.x, b1v.y, b1v.z, b1v.w};
            #pragma unroll
            for (int i = 0; i < 4; ++i)
                #pragma unroll
                for (int j = 0; j < 8; ++j)
                    acc[i][j] += av[i] * bv[j];
        }
        __syncthreads();
    }

    #pragma unroll
    for (int i = 0; i < 4; ++i) {
        int node = m0 + ty * 4 + i;
        if (node >= N_NODES) continue;
        #pragma unroll
        for (int j = 0; j < 8; ++j) {
            int col = (j < 4) ? (tx * 4 + j) : (64 + tx * 4 + (j - 4));
            out[(size_t)node * DIM + col] = acc[i][j] + b2[col];
        }
    }
}

// ---------------------------------------------------------------------------
extern "C" void kernel_launch(void* const* d_in, const int* in_sizes, int n_in,
                              void* d_out, int out_size, void* d_ws, size_t ws_size,
                              hipStream_t stream) {
    const float* h  = (const float*)d_in[0];
    const int*   ei = (const int*)d_in[1];
    const float* W1 = (const float*)d_in[2];
    const float* b1 = (const float*)d_in[3];
    const float* W2 = (const float*)d_in[4];
    const float* b2 = (const float*)d_in[5];
    float* out = (float*)d_out;

    float* accum = (float*)d_ws;                         // N*DIM
    float* deg   = accum + (size_t)N_NODES * DIM;        // N
    float* hdn   = deg + N_NODES;                        // N*HID

    hipMemsetAsync(accum, 0, (size_t)(N_NODES * DIM + N_NODES) * sizeof(float), stream);

    mgl_scatter_kernel<<<(EDGES + 7) / 8, 256, 0, stream>>>(h, ei, accum, deg);

    int mtiles = (N_NODES + 63) / 64;  // 1563
    mgl_mlp1_kernel<<<dim3(mtiles, 4), 256, 0, stream>>>(h, accum, deg, W1, b1, hdn);
    mgl_mlp2_kernel<<<mtiles, 256, 0, stream>>>(hdn, W2, b2, out);
}

// Round 2
// 767.047 us; speedup vs baseline: 2.2147x; 2.2147x over previous
//
#include <hip/hip_runtime.h>
#include <hip/hip_bf16.h>
#include <math.h>

#define N_NODES 100000
#define DIM 128
#define HID 512
#define EDGES 600000
#define SCAN_CHUNK 1024
#define SCAN_NBLK ((N_NODES + SCAN_CHUNK - 1) / SCAN_CHUNK)  // 98

__device__ inline unsigned short f32_to_bf16(float f) {
    unsigned int u = __float_as_uint(f);
    u += 0x7fff + ((u >> 16) & 1);
    return (unsigned short)(u >> 16);
}
__device__ inline float bf16_to_f32(unsigned short s) {
    return __uint_as_float(((unsigned int)s) << 16);
}

// ---------------------------------------------------------------------------
// CSR build: count, scan, fill
// ---------------------------------------------------------------------------
__global__ __launch_bounds__(256) void mgl_count_kernel(
    const int* __restrict__ ei, int* __restrict__ cnt)
{
    int e = blockIdx.x * 256 + threadIdx.x;
    if (e < EDGES) atomicAdd(&cnt[ei[EDGES + e]], 1);
}

__global__ __launch_bounds__(256) void mgl_scan_block_kernel(
    const int* __restrict__ cnt, int* __restrict__ row_start, int* __restrict__ bsum)
{
    __shared__ int sdata[256];
    int t = threadIdx.x;
    int base = blockIdx.x * SCAN_CHUNK + t * 4;
    int v[4];
    #pragma unroll
    for (int i = 0; i < 4; ++i) {
        int idx = base + i;
        v[i] = (idx < N_NODES) ? cnt[idx] : 0;
    }
    int tsum = v[0] + v[1] + v[2] + v[3];
    sdata[t] = tsum;
    __syncthreads();
    for (int off = 1; off < 256; off <<= 1) {
        int x = (t >= off) ? sdata[t - off] : 0;
        __syncthreads();
        sdata[t] += x;
        __syncthreads();
    }
    int run = (t > 0) ? sdata[t - 1] : 0;
    #pragma unroll
    for (int i = 0; i < 4; ++i) {
        int idx = base + i;
        if (idx < N_NODES) row_start[idx] = run;
        run += v[i];
    }
    if (t == 255) bsum[blockIdx.x] = sdata[255];
}

__global__ __launch_bounds__(128) void mgl_scan_bsum_kernel(int* __restrict__ bsum)
{
    __shared__ int sd[128];
    int t = threadIdx.x;
    int v = (t < SCAN_NBLK) ? bsum[t] : 0;
    sd[t] = v;
    __syncthreads();
    for (int off = 1; off < 128; off <<= 1) {
        int x = (t >= off) ? sd[t - off] : 0;
        __syncthreads();
        sd[t] += x;
        __syncthreads();
    }
    if (t < SCAN_NBLK) bsum[t] = sd[t] - v;  // exclusive
}

__global__ __launch_bounds__(256) void mgl_scan_add_kernel(
    int* __restrict__ row_start, const int* __restrict__ bsum)
{
    int i = blockIdx.x * 256 + threadIdx.x;
    if (i < N_NODES) row_start[i] += bsum[i / SCAN_CHUNK];
    if (i == 0) row_start[N_NODES] = EDGES;
}

__global__ __launch_bounds__(256) void mgl_fill_kernel(
    const int* __restrict__ ei, const int* __restrict__ row_start,
    int* __restrict__ cursor, int* __restrict__ csr)
{
    int e = blockIdx.x * 256 + threadIdx.x;
    if (e >= EDGES) return;
    int s = ei[e];
    int t = ei[EDGES + e];
    int pos = atomicAdd(&cursor[t], 1);
    csr[row_start[t] + pos] = s;
}

// ---------------------------------------------------------------------------
// Gather-mean: one wave per node, float2 per lane (128 dims / 64 lanes)
// ---------------------------------------------------------------------------
__global__ __launch_bounds__(256) void mgl_gather_mean_kernel(
    const float* __restrict__ h, const int* __restrict__ row_start,
    const int* __restrict__ csr, float* __restrict__ agg)
{
    int v = blockIdx.x * 4 + (threadIdx.x >> 6);
    if (v >= N_NODES) return;
    int lane = threadIdx.x & 63;
    int beg = row_start[v];
    int end = row_start[v + 1];
    float2 acc = make_float2(0.f, 0.f);
    for (int i = beg; i < end; ++i) {
        int s = csr[i];  // wave-uniform broadcast
        float2 x = *(const float2*)(h + (size_t)s * DIM + lane * 2);
        acc.x += x.x;
        acc.y += x.y;
    }
    float2 res;
    if (end > beg) {
        float inv = 1.f / (float)(end - beg);
        res = make_float2(acc.x * inv, acc.y * inv);
    } else {
        res = *(const float2*)(h + (size_t)v * DIM + lane * 2);
    }
    *(float2*)(agg + (size_t)v * DIM + lane * 2) = res;
}

// ---------------------------------------------------------------------------
// MLP1: hdn(bf16) = gelu( [h, agg] @ W1 + b1 )
// BM=64, BN=128, BK=64, 256 threads (16x16), 4x8 micro-tile per thread
// ---------------------------------------------------------------------------
__global__ __launch_bounds__(256) void mgl_mlp1_kernel(
    const float* __restrict__ h, const float* __restrict__ agg,
    const float* __restrict__ W1, const float* __restrict__ b1,
    unsigned short* __restrict__ hdn)
{
    __shared__ float XsT[64][68];   // [k][m]
    __shared__ float Ws[64][132];   // [k][n]

    int tid = threadIdx.x;
    int ty = tid >> 4;
    int tx = tid & 15;
    int m0 = blockIdx.x * 64;
    int n0 = blockIdx.y * 128;

    float acc[4][8];
    #pragma unroll
    for (int i = 0; i < 4; ++i)
        #pragma unroll
        for (int j = 0; j < 8; ++j) acc[i][j] = 0.f;

    for (int kt = 0; kt < 4; ++kt) {
        {
            int r = tid >> 4;
            int c = tid & 15;
            int kg = kt * 64 + c * 4;
            #pragma unroll
            for (int it = 0; it < 4; ++it) {
                int row = r + 16 * it;
                int node = m0 + row;
                int nc = node < N_NODES ? node : N_NODES - 1;
                float4 v;
                if (kg < DIM) v = *(const float4*)(h + (size_t)nc * DIM + kg);
                else          v = *(const float4*)(agg + (size_t)nc * DIM + (kg - DIM));
                XsT[c * 4 + 0][row] = v.x;
                XsT[c * 4 + 1][row] = v.y;
                XsT[c * 4 + 2][row] = v.z;
                XsT[c * 4 + 3][row] = v.w;
            }
        }
        {
            int kr = tid >> 5;
            int c4 = tid & 31;
            #pragma unroll
            for (int it = 0; it < 8; ++it) {
                int k = kr + 8 * it;
                float4 w = *(const float4*)(W1 + (size_t)(kt * 64 + k) * HID + n0 + c4 * 4);
                *(float4*)&Ws[k][c4 * 4] = w;
            }
        }
        __syncthreads();
        #pragma unroll
        for (int k = 0; k < 64; ++k) {
            float4 a4 = *(const float4*)&XsT[k][ty * 4];
            float4 b0 = *(const float4*)&Ws[k][tx * 4];
            float4 b1v = *(const float4*)&Ws[k][64 + tx * 4];
            float av[4] = {a4.x, a4.y, a4.z, a4.w};
            float bv[8] = {b0.x, b0.y, b0.z, b0.w, b1v.x, b1v.y, b1v.z, b1v.w};
            #pragma unroll
            for (int i = 0; i < 4; ++i)
                #pragma unroll
                for (int j = 0; j < 8; ++j)
                    acc[i][j] += av[i] * bv[j];
        }
        __syncthreads();
    }

    #pragma unroll
    for (int i = 0; i < 4; ++i) {
        int node = m0 + ty * 4 + i;
        if (node >= N_NODES) continue;
        #pragma unroll
        for (int g = 0; g < 2; ++g) {
            ushort4 pack;
            unsigned short* pp = (unsigned short*)&pack;
            #pragma unroll
            for (int j = 0; j < 4; ++j) {
                int col = g * 64 + tx * 4 + j;
                float x = acc[i][g * 4 + j] + b1[n0 + col];
                float gl = 0.5f * x * (1.0f + erff(x * 0.70710678118654752f));
                pp[j] = f32_to_bf16(gl);
            }
            *(ushort4*)(hdn + (size_t)node * HID + n0 + g * 64 + tx * 4) = pack;
        }
    }
}

// ---------------------------------------------------------------------------
// MLP2: out = hdn(bf16) @ W2 + b2
// ---------------------------------------------------------------------------
__global__ __launch_bounds__(256) void mgl_mlp2_kernel(
    const unsigned short* __restrict__ hdn, const float* __restrict__ W2,
    const float* __restrict__ b2, float* __restrict__ out)
{
    __shared__ float AsT[64][68];
    __shared__ float Ws[64][132];

    int tid = threadIdx.x;
    int ty = tid >> 4;
    int tx = tid & 15;
    int m0 = blockIdx.x * 64;

    float acc[4][8];
    #pragma unroll
    for (int i = 0; i < 4; ++i)
        #pragma unroll
        for (int j = 0; j < 8; ++j) acc[i][j] = 0.f;

    for (int kt = 0; kt < 8; ++kt) {
        {
            int r = tid >> 4;
            int c = tid & 15;
            #pragma unroll
            for (int it = 0; it < 4; ++it) {
                int row = r + 16 * it;
                int node = m0 + row;
                int nc = node < N_NODES ? node : N_NODES - 1;
                ushort4 q = *(const ushort4*)(hdn + (size_t)nc * HID + kt * 64 + c * 4);
                AsT[c * 4 + 0][row] = bf16_to_f32(q.x);
                AsT[c * 4 + 1][row] = bf16_to_f32(q.y);
                AsT[c * 4 + 2][row] = bf16_to_f32(q.z);
                AsT[c * 4 + 3][row] = bf16_to_f32(q.w);
            }
        }
        {
            int kr = tid >> 5;
            int c4 = tid & 31;
            #pragma unroll
            for (int it = 0; it < 8; ++it) {
                int k = kr + 8 * it;
                float4 w = *(const float4*)(W2 + (size_t)(kt * 64 + k) * DIM + c4 * 4);
                *(float4*)&Ws[k][c4 * 4] = w;
            }
        }
        __syncthreads();
        #pragma unroll
        for (int k = 0; k < 64; ++k) {
            float4 a4 = *(const float4*)&AsT[k][ty * 4];
            float4 b0 = *(const float4*)&Ws[k][tx * 4];
            float4 b1v = *(const float4*)&Ws[k][64 + tx * 4];
            float av[4] = {a4.x, a4.y, a4.z, a4.w};
            float bv[8] = {b0.x, b0.y, b0.z, b0.w, b1v.x, b1v.y, b1v.z, b1v.w};
            #pragma unroll
            for (int i = 0; i < 4; ++i)
                #pragma unroll
                for (int j = 0; j < 8; ++j)
                    acc[i][j] += av[i] * bv[j];
        }
        __syncthreads();
    }

    #pragma unroll
    for (int i = 0; i < 4; ++i) {
        int node = m0 + ty * 4 + i;
        if (node >= N_NODES) continue;
        #pragma unroll
        for (int j = 0; j < 8; ++j) {
            int col = (j < 4) ? (tx * 4 + j) : (64 + tx * 4 + (j - 4));
            out[(size_t)node * DIM + col] = acc[i][j] + b2[col];
        }
    }
}

// ---------------------------------------------------------------------------
extern "C" void kernel_launch(void* const* d_in, const int* in_sizes, int n_in,
                              void* d_out, int out_size, void* d_ws, size_t ws_size,
                              hipStream_t stream) {
    const float* h  = (const float*)d_in[0];
    const int*   ei = (const int*)d_in[1];
    const float* W1 = (const float*)d_in[2];
    const float* b1 = (const float*)d_in[3];
    const float* W2 = (const float*)d_in[4];
    const float* b2 = (const float*)d_in[5];
    float* out = (float*)d_out;

    // workspace layout
    float* agg = (float*)d_ws;                                     // N*DIM f32
    unsigned short* hdn = (unsigned short*)(agg + (size_t)N_NODES * DIM);  // N*HID bf16
    int* cnt = (int*)(hdn + (size_t)N_NODES * HID);                // N (also cursor)
    int* row_start = cnt + N_NODES;                                // N+1
    int* bsum = row_start + N_NODES + 1;                           // SCAN_NBLK
    int* csr = bsum + 128;                                         // E

    hipMemsetAsync(cnt, 0, N_NODES * sizeof(int), stream);
    mgl_count_kernel<<<(EDGES + 255) / 256, 256, 0, stream>>>(ei, cnt);
    mgl_scan_block_kernel<<<SCAN_NBLK, 256, 0, stream>>>(cnt, row_start, bsum);
    mgl_scan_bsum_kernel<<<1, 128, 0, stream>>>(bsum);
    mgl_scan_add_kernel<<<(N_NODES + 255) / 256, 256, 0, stream>>>(row_start, bsum);
    hipMemsetAsync(cnt, 0, N_NODES * sizeof(int), stream);  // reuse as cursor
    mgl_fill_kernel<<<(EDGES + 255) / 256, 256, 0, stream>>>(ei, row_start, cnt, csr);
    mgl_gather_mean_kernel<<<(N_NODES + 3) / 4, 256, 0, stream>>>(h, row_start, csr, agg);

    int mtiles = (N_NODES + 63) / 64;  // 1563
    mgl_mlp1_kernel<<<dim3(mtiles, 4), 256, 0, stream>>>(h, agg, W1, b1, hdn);
    mgl_mlp2_kernel<<<mtiles, 256, 0, stream>>>(hdn, W2, b2, out);
}

// Round 3
// 274.008 us; speedup vs baseline: 6.1999x; 2.7994x over previous
//
#include <hip/hip_runtime.h>
#include <hip/hip_bf16.h>
#include <math.h>

#define N_NODES 100000
#define DIM 128
#define HID 512
#define EDGES 600000
#define SCAN_CHUNK 1024
#define SCAN_NBLK ((N_NODES + SCAN_CHUNK - 1) / SCAN_CHUNK)  // 98
#define MROWS_PAD 100096   // 782 * 128

typedef short bf16x8 __attribute__((ext_vector_type(8)));
typedef float f32x4 __attribute__((ext_vector_type(4)));

__device__ inline unsigned short f32_to_bf16(float f) {
    unsigned int u = __float_as_uint(f);
    u += 0x7fff + ((u >> 16) & 1);
    return (unsigned short)(u >> 16);
}

__device__ inline void gload16(const void* g, void* l) {
    __builtin_amdgcn_global_load_lds(
        (const __attribute__((address_space(1))) unsigned int*)g,
        (__attribute__((address_space(3))) unsigned int*)l,
        16, 0, 0);
}

// ---------------------------------------------------------------------------
// CSR build: count, scan, fill
// ---------------------------------------------------------------------------
__global__ __launch_bounds__(256) void mgl_count_kernel(
    const int* __restrict__ ei, int* __restrict__ cnt)
{
    int e = blockIdx.x * 256 + threadIdx.x;
    if (e < EDGES) atomicAdd(&cnt[ei[EDGES + e]], 1);
}

__global__ __launch_bounds__(256) void mgl_scan_block_kernel(
    const int* __restrict__ cnt, int* __restrict__ row_start, int* __restrict__ bsum)
{
    __shared__ int sdata[256];
    int t = threadIdx.x;
    int base = blockIdx.x * SCAN_CHUNK + t * 4;
    int v[4];
    #pragma unroll
    for (int i = 0; i < 4; ++i) {
        int idx = base + i;
        v[i] = (idx < N_NODES) ? cnt[idx] : 0;
    }
    int tsum = v[0] + v[1] + v[2] + v[3];
    sdata[t] = tsum;
    __syncthreads();
    for (int off = 1; off < 256; off <<= 1) {
        int x = (t >= off) ? sdata[t - off] : 0;
        __syncthreads();
        sdata[t] += x;
        __syncthreads();
    }
    int run = (t > 0) ? sdata[t - 1] : 0;
    #pragma unroll
    for (int i = 0; i < 4; ++i) {
        int idx = base + i;
        if (idx < N_NODES) row_start[idx] = run;
        run += v[i];
    }
    if (t == 255) bsum[blockIdx.x] = sdata[255];
}

__global__ __launch_bounds__(128) void mgl_scan_bsum_kernel(int* __restrict__ bsum)
{
    __shared__ int sd[128];
    int t = threadIdx.x;
    int v = (t < SCAN_NBLK) ? bsum[t] : 0;
    sd[t] = v;
    __syncthreads();
    for (int off = 1; off < 128; off <<= 1) {
        int x = (t >= off) ? sd[t - off] : 0;
        __syncthreads();
        sd[t] += x;
        __syncthreads();
    }
    if (t < SCAN_NBLK) bsum[t] = sd[t] - v;  // exclusive
}

__global__ __launch_bounds__(256) void mgl_scan_add_kernel(
    int* __restrict__ row_start, const int* __restrict__ bsum)
{
    int i = blockIdx.x * 256 + threadIdx.x;
    if (i < N_NODES) row_start[i] += bsum[i / SCAN_CHUNK];
    if (i == 0) row_start[N_NODES] = EDGES;
}

__global__ __launch_bounds__(256) void mgl_fill_kernel(
    const int* __restrict__ ei, const int* __restrict__ row_start,
    int* __restrict__ cursor, int* __restrict__ csr)
{
    int e = blockIdx.x * 256 + threadIdx.x;
    if (e >= EDGES) return;
    int s = ei[e];
    int t = ei[EDGES + e];
    int pos = atomicAdd(&cursor[t], 1);
    csr[row_start[t] + pos] = s;
}

// ---------------------------------------------------------------------------
// h -> bf16 into X[:, 0:128]
// ---------------------------------------------------------------------------
__global__ __launch_bounds__(256) void mgl_convert_h_kernel(
    const float* __restrict__ h, unsigned short* __restrict__ X)
{
    int t = blockIdx.x * 256 + threadIdx.x;
    if (t >= N_NODES * (DIM / 4)) return;
    int node = t >> 5;          // DIM/4 = 32 float4 per node
    int c4 = t & 31;
    float4 v = *(const float4*)(h + (size_t)node * DIM + c4 * 4);
    ushort4 p;
    p.x = f32_to_bf16(v.x); p.y = f32_to_bf16(v.y);
    p.z = f32_to_bf16(v.z); p.w = f32_to_bf16(v.w);
    *(ushort4*)(X + (size_t)node * 256 + c4 * 4) = p;
}

// ---------------------------------------------------------------------------
// Gather-mean (one wave/node) -> bf16 into X[:, 128:256]
// ---------------------------------------------------------------------------
__global__ __launch_bounds__(256) void mgl_gather_mean_kernel(
    const float* __restrict__ h, const int* __restrict__ row_start,
    const int* __restrict__ csr, unsigned short* __restrict__ X)
{
    int v = blockIdx.x * 4 + (threadIdx.x >> 6);
    if (v >= N_NODES) return;
    int lane = threadIdx.x & 63;
    int beg = row_start[v];
    int end = row_start[v + 1];
    float2 acc = make_float2(0.f, 0.f);
    for (int i = beg; i < end; ++i) {
        int s = csr[i];  // wave-uniform broadcast
        float2 x = *(const float2*)(h + (size_t)s * DIM + lane * 2);
        acc.x += x.x;
        acc.y += x.y;
    }
    float2 res;
    if (end > beg) {
        float inv = 1.f / (float)(end - beg);
        res = make_float2(acc.x * inv, acc.y * inv);
    } else {
        res = *(const float2*)(h + (size_t)v * DIM + lane * 2);
    }
    unsigned int pk = (unsigned int)f32_to_bf16(res.x) |
                      ((unsigned int)f32_to_bf16(res.y) << 16);
    *(unsigned int*)(X + (size_t)v * 256 + 128 + lane * 2) = pk;
}

// ---------------------------------------------------------------------------
// Weight transposes -> bf16 [out][in]
// ---------------------------------------------------------------------------
__global__ __launch_bounds__(256) void mgl_transpose_w1_kernel(
    const float* __restrict__ W1, unsigned short* __restrict__ W1T)
{
    int n = blockIdx.x;            // 0..511
    int k = threadIdx.x;           // 0..255
    W1T[(size_t)n * 256 + k] = f32_to_bf16(W1[(size_t)k * HID + n]);
}

__global__ __launch_bounds__(256) void mgl_transpose_w2_kernel(
    const float* __restrict__ W2, unsigned short* __restrict__ W2T)
{
    int n = blockIdx.x;            // 0..127
    #pragma unroll
    for (int it = 0; it < 2; ++it) {
        int k = threadIdx.x + it * 256;  // 0..511
        W2T[(size_t)n * 512 + k] = f32_to_bf16(W2[(size_t)k * DIM + n]);
    }
}

// ---------------------------------------------------------------------------
// MFMA GEMM: out[m][n] = f( sum_k Xr[m][k] * Wt[n][k] + bias[n] )
// 128x128 tile, BK=64, 4 waves, 16x16x32 bf16 MFMA, swapped operands so each
// lane's 4 acc regs are 4 consecutive n columns.
// ---------------------------------------------------------------------------
template<int KTOT, bool GELU_OUT>
__global__ __launch_bounds__(256) void mgl_gemm_kernel(
    const unsigned short* __restrict__ Wt,   // [ntot][KTOT] bf16
    const unsigned short* __restrict__ Xr,   // [>=N_NODES][KTOT] bf16
    const float* __restrict__ bias,          // [ntot]
    void* __restrict__ outp)
{
    __shared__ unsigned short ldsW[128 * 64];  // 16 KB  [n_local][k_local]
    __shared__ unsigned short ldsX[128 * 64];  // 16 KB  [m_local][k_local]

    int tid = threadIdx.x;
    int w = tid >> 6;
    int l = tid & 63;
    int m0 = blockIdx.x * 128;
    int n0 = blockIdx.y * 128;
    int wm = w >> 1;          // 0..1
    int wn = w & 1;           // 0..1
    int r16 = l & 15;
    int kq = l >> 4;          // 0..3

    f32x4 acc[4][4] = {};

    for (int kt = 0; kt < KTOT / 64; ++kt) {
        // ---- stage W tile (128 n x 64 k) ----
        #pragma unroll
        for (int i = 0; i < 4; ++i) {
            int loff = i * 4096 + w * 1024 + l * 16;   // byte offset in tile
            int row = loff >> 7;                        // /128B per row
            int c8 = (loff >> 4) & 7;                   // which 8-bf16 group
            const unsigned short* g = Wt + (size_t)(n0 + row) * KTOT + kt * 64 + c8 * 8;
            gload16(g, (char*)ldsW + i * 4096 + w * 1024);
        }
        // ---- stage X tile (128 m x 64 k), clamp tail rows ----
        #pragma unroll
        for (int i = 0; i < 4; ++i) {
            int loff = i * 4096 + w * 1024 + l * 16;
            int row = loff >> 7;
            int c8 = (loff >> 4) & 7;
            int gm = m0 + row;
            if (gm > N_NODES - 1) gm = N_NODES - 1;
            const unsigned short* g = Xr + (size_t)gm * KTOT + kt * 64 + c8 * 8;
            gload16(g, (char*)ldsX + i * 4096 + w * 1024);
        }
        __syncthreads();   // drains vmcnt, LDS visible to all waves

        #pragma unroll
        for (int kk = 0; kk < 2; ++kk) {
            bf16x8 a[4], b[4];
            #pragma unroll
            for (int ni = 0; ni < 4; ++ni)
                a[ni] = *(const bf16x8*)((const char*)ldsW +
                          (wn * 64 + ni * 16 + r16) * 128 + kk * 64 + kq * 16);
            #pragma unroll
            for (int mi = 0; mi < 4; ++mi)
                b[mi] = *(const bf16x8*)((const char*)ldsX +
                          (wm * 64 + mi * 16 + r16) * 128 + kk * 64 + kq * 16);
            #pragma unroll
            for (int mi = 0; mi < 4; ++mi)
                #pragma unroll
                for (int ni = 0; ni < 4; ++ni)
                    acc[mi][ni] = __builtin_amdgcn_mfma_f32_16x16x32_bf16(
                        a[ni], b[mi], acc[mi][ni], 0, 0, 0);
        }
        __syncthreads();   // all reads done before next stage overwrites
    }

    // ---- epilogue ----
    #pragma unroll
    for (int mi = 0; mi < 4; ++mi) {
        int m = m0 + wm * 64 + mi * 16 + r16;
        if (m >= N_NODES) continue;
        #pragma unroll
        for (int ni = 0; ni < 4; ++ni) {
            int nc = n0 + wn * 64 + ni * 16 + kq * 4;   // 4 consecutive n
            float4 bv = *(const float4*)(bias + nc);
            float x0 = acc[mi][ni][0] + bv.x;
            float x1 = acc[mi][ni][1] + bv.y;
            float x2 = acc[mi][ni][2] + bv.z;
            float x3 = acc[mi][ni][3] + bv.w;
            if (GELU_OUT) {
                const float s = 0.70710678118654752f;
                float g0 = 0.5f * x0 * (1.0f + erff(x0 * s));
                float g1 = 0.5f * x1 * (1.0f + erff(x1 * s));
                float g2 = 0.5f * x2 * (1.0f + erff(x2 * s));
                float g3 = 0.5f * x3 * (1.0f + erff(x3 * s));
                ushort4 p;
                p.x = f32_to_bf16(g0); p.y = f32_to_bf16(g1);
                p.z = f32_to_bf16(g2); p.w = f32_to_bf16(g3);
                *(ushort4*)((unsigned short*)outp + (size_t)m * HID + nc) = p;
            } else {
                float4 o = make_float4(x0, x1, x2, x3);
                *(float4*)((float*)outp + (size_t)m * DIM + nc) = o;
            }
        }
    }
}

// ---------------------------------------------------------------------------
extern "C" void kernel_launch(void* const* d_in, const int* in_sizes, int n_in,
                              void* d_out, int out_size, void* d_ws, size_t ws_size,
                              hipStream_t stream) {
    const float* h  = (const float*)d_in[0];
    const int*   ei = (const int*)d_in[1];
    const float* W1 = (const float*)d_in[2];
    const float* b1 = (const float*)d_in[3];
    const float* W2 = (const float*)d_in[4];
    const float* b2 = (const float*)d_in[5];
    float* out = (float*)d_out;

    // workspace layout
    unsigned short* X   = (unsigned short*)d_ws;             // MROWS_PAD*256 bf16
    unsigned short* hdn = X + (size_t)MROWS_PAD * 256;       // MROWS_PAD*512 bf16
    unsigned short* W1T = hdn + (size_t)MROWS_PAD * 512;     // 512*256 bf16
    unsigned short* W2T = W1T + 512 * 256;                   // 128*512 bf16
    int* cnt = (int*)(W2T + 128 * 512);                      // N (also cursor)
    int* row_start = cnt + N_NODES;                          // N+1
    int* bsum = row_start + N_NODES + 1;                     // 128
    int* csr = bsum + 128;                                   // E

    // prep (independent of CSR)
    mgl_transpose_w1_kernel<<<512, 256, 0, stream>>>(W1, W1T);
    mgl_transpose_w2_kernel<<<128, 256, 0, stream>>>(W2, W2T);
    mgl_convert_h_kernel<<<(N_NODES * 32 + 255) / 256, 256, 0, stream>>>(h, X);

    // CSR build
    hipMemsetAsync(cnt, 0, N_NODES * sizeof(int), stream);
    mgl_count_kernel<<<(EDGES + 255) / 256, 256, 0, stream>>>(ei, cnt);
    mgl_scan_block_kernel<<<SCAN_NBLK, 256, 0, stream>>>(cnt, row_start, bsum);
    mgl_scan_bsum_kernel<<<1, 128, 0, stream>>>(bsum);
    mgl_scan_add_kernel<<<(N_NODES + 255) / 256, 256, 0, stream>>>(row_start, bsum);
    hipMemsetAsync(cnt, 0, N_NODES * sizeof(int), stream);  // reuse as cursor
    mgl_fill_kernel<<<(EDGES + 255) / 256, 256, 0, stream>>>(ei, row_start, cnt, csr);
    mgl_gather_mean_kernel<<<(N_NODES + 3) / 4, 256, 0, stream>>>(h, row_start, csr, X);

    // MLP via MFMA
    int mtiles = MROWS_PAD / 128;  // 782
    mgl_gemm_kernel<256, true><<<dim3(mtiles, 4), 256, 0, stream>>>(W1T, X, b1, hdn);
    mgl_gemm_kernel<512, false><<<dim3(mtiles, 1), 256, 0, stream>>>(W2T, hdn, b2, out);
}

// Round 4
// 262.493 us; speedup vs baseline: 6.4718x; 1.0439x over previous
//
#include <hip/hip_runtime.h>
#include <hip/hip_bf16.h>
#include <math.h>

#define N_NODES 100000
#define DIM 128
#define HID 512
#define EDGES 600000
#define SCAN_CHUNK 1024
#define SCAN_NBLK ((N_NODES + SCAN_CHUNK - 1) / SCAN_CHUNK)  // 98
#define MROWS_PAD 100096   // 782 * 128

typedef short bf16x8 __attribute__((ext_vector_type(8)));
typedef float f32x4 __attribute__((ext_vector_type(4)));

// Swizzle convention (rule #21 both-sides): for every bf16 staging buffer
// (X, W1T, W2T, hdn), physical byte offset within a row = logical byte
// offset XOR ((row & 7) << 4). global_load_lds stages rows linearly, the
// MFMA fragment ds_read applies the same XOR -> conflict-free LDS banks.

__device__ inline unsigned short f32_to_bf16(float f) {
    unsigned int u = __float_as_uint(f);
    u += 0x7fff + ((u >> 16) & 1);
    return (unsigned short)(u >> 16);
}

__device__ inline void gload16(const void* g, void* l) {
    __builtin_amdgcn_global_load_lds(
        (const __attribute__((address_space(1))) unsigned int*)g,
        (__attribute__((address_space(3))) unsigned int*)l,
        16, 0, 0);
}

// ---------------------------------------------------------------------------
// CSR build: count, scan, fill
// ---------------------------------------------------------------------------
__global__ __launch_bounds__(256) void mgl_count_kernel(
    const int* __restrict__ ei, int* __restrict__ cnt)
{
    int e = blockIdx.x * 256 + threadIdx.x;
    if (e < EDGES) atomicAdd(&cnt[ei[EDGES + e]], 1);
}

__global__ __launch_bounds__(256) void mgl_scan_block_kernel(
    const int* __restrict__ cnt, int* __restrict__ row_start, int* __restrict__ bsum)
{
    __shared__ int sdata[256];
    int t = threadIdx.x;
    int base = blockIdx.x * SCAN_CHUNK + t * 4;
    int v[4];
    #pragma unroll
    for (int i = 0; i < 4; ++i) {
        int idx = base + i;
        v[i] = (idx < N_NODES) ? cnt[idx] : 0;
    }
    int tsum = v[0] + v[1] + v[2] + v[3];
    sdata[t] = tsum;
    __syncthreads();
    for (int off = 1; off < 256; off <<= 1) {
        int x = (t >= off) ? sdata[t - off] : 0;
        __syncthreads();
        sdata[t] += x;
        __syncthreads();
    }
    int run = (t > 0) ? sdata[t - 1] : 0;
    #pragma unroll
    for (int i = 0; i < 4; ++i) {
        int idx = base + i;
        if (idx < N_NODES) row_start[idx] = run;
        run += v[i];
    }
    if (t == 255) bsum[blockIdx.x] = sdata[255];
}

__global__ __launch_bounds__(128) void mgl_scan_bsum_kernel(int* __restrict__ bsum)
{
    __shared__ int sd[128];
    int t = threadIdx.x;
    int v = (t < SCAN_NBLK) ? bsum[t] : 0;
    sd[t] = v;
    __syncthreads();
    for (int off = 1; off < 128; off <<= 1) {
        int x = (t >= off) ? sd[t - off] : 0;
        __syncthreads();
        sd[t] += x;
        __syncthreads();
    }
    if (t < SCAN_NBLK) bsum[t] = sd[t] - v;  // exclusive
}

__global__ __launch_bounds__(256) void mgl_scan_add_kernel(
    int* __restrict__ row_start, const int* __restrict__ bsum)
{
    int i = blockIdx.x * 256 + threadIdx.x;
    if (i < N_NODES) row_start[i] += bsum[i / SCAN_CHUNK];
    if (i == 0) row_start[N_NODES] = EDGES;
}

__global__ __launch_bounds__(256) void mgl_fill_kernel(
    const int* __restrict__ ei, const int* __restrict__ row_start,
    int* __restrict__ cursor, int* __restrict__ csr)
{
    int e = blockIdx.x * 256 + threadIdx.x;
    if (e >= EDGES) return;
    int s = ei[e];
    int t = ei[EDGES + e];
    int pos = atomicAdd(&cursor[t], 1);
    csr[row_start[t] + pos] = s;
}

// ---------------------------------------------------------------------------
// h -> bf16 into X[:, 0:128]  (swizzled layout)
// ---------------------------------------------------------------------------
__global__ __launch_bounds__(256) void mgl_convert_h_kernel(
    const float* __restrict__ h, unsigned short* __restrict__ X)
{
    int t = blockIdx.x * 256 + threadIdx.x;
    if (t >= N_NODES * (DIM / 4)) return;
    int node = t >> 5;          // 32 float4 per node
    int c4 = t & 31;
    float4 v = *(const float4*)(h + (size_t)node * DIM + c4 * 4);
    ushort4 p;
    p.x = f32_to_bf16(v.x); p.y = f32_to_bf16(v.y);
    p.z = f32_to_bf16(v.z); p.w = f32_to_bf16(v.w);
    int byteoff = (c4 * 8) ^ ((node & 7) << 4);
    *(ushort4*)((char*)(X + (size_t)node * 256) + byteoff) = p;
}

// ---------------------------------------------------------------------------
// Gather-mean (one wave/node), reads bf16 X[:,0:128], writes bf16 X[:,128:256]
// ---------------------------------------------------------------------------
__global__ __launch_bounds__(256) void mgl_gather_mean_kernel(
    const unsigned short* __restrict__ Xb, const int* __restrict__ row_start,
    const int* __restrict__ csr, unsigned short* __restrict__ X)
{
    int v = blockIdx.x * 4 + (threadIdx.x >> 6);
    if (v >= N_NODES) return;
    int lane = threadIdx.x & 63;
    int beg = row_start[v];
    int end = row_start[v + 1];
    int laneByte = lane * 4;              // logical byte of elements {2*lane, 2*lane+1}
    const char* xb = (const char*)Xb;

    if (end > beg) {
        float2 acc = make_float2(0.f, 0.f);
        for (int i = beg; i < end; ++i) {
            int s = csr[i];  // wave-uniform
            unsigned int pk = *(const unsigned int*)(
                xb + (size_t)s * 512 + (laneByte ^ ((s & 7) << 4)));
            acc.x += __uint_as_float(pk << 16);
            acc.y += __uint_as_float(pk & 0xffff0000u);
        }
        float inv = 1.f / (float)(end - beg);
        unsigned int po = (unsigned int)f32_to_bf16(acc.x * inv) |
                          ((unsigned int)f32_to_bf16(acc.y * inv) << 16);
        *(unsigned int*)((char*)(X + (size_t)v * 256) +
                         ((256 + laneByte) ^ ((v & 7) << 4))) = po;
    } else {
        // isolated node: copy own bf16 row
        unsigned int pk = *(const unsigned int*)(
            xb + (size_t)v * 512 + (laneByte ^ ((v & 7) << 4)));
        *(unsigned int*)((char*)(X + (size_t)v * 256) +
                         ((256 + laneByte) ^ ((v & 7) << 4))) = pk;
    }
}

// ---------------------------------------------------------------------------
// Weight transposes -> bf16 [out][in], swizzled
// ---------------------------------------------------------------------------
__global__ __launch_bounds__(256) void mgl_transpose_w1_kernel(
    const float* __restrict__ W1, unsigned short* __restrict__ W1T)
{
    int n = blockIdx.x;            // 0..511
    int k = threadIdx.x;           // 0..255
    unsigned short val = f32_to_bf16(W1[(size_t)k * HID + n]);
    int byteoff = (k * 2) ^ ((n & 7) << 4);
    *(unsigned short*)((char*)(W1T + (size_t)n * 256) + byteoff) = val;
}

__global__ __launch_bounds__(256) void mgl_transpose_w2_kernel(
    const float* __restrict__ W2, unsigned short* __restrict__ W2T)
{
    int n = blockIdx.x;            // 0..127
    #pragma unroll
    for (int it = 0; it < 2; ++it) {
        int k = threadIdx.x + it * 256;  // 0..511
        unsigned short val = f32_to_bf16(W2[(size_t)k * DIM + n]);
        int byteoff = (k * 2) ^ ((n & 7) << 4);
        *(unsigned short*)((char*)(W2T + (size_t)n * 512) + byteoff) = val;
    }
}

// ---------------------------------------------------------------------------
// MFMA GEMM: out[m][n] = f( sum_k Xr[m][k] * Wt[n][k] + bias[n] )
// 128x128 tile, BK=64, 4 waves, double-buffered LDS, counted vmcnt pipeline,
// XOR-swizzled LDS (pre-swizzled global), setprio around MFMA cluster.
// ---------------------------------------------------------------------------
template<int KTOT, int NY, bool GELU_OUT>
__global__ __launch_bounds__(256) void mgl_gemm_kernel(
    const unsigned short* __restrict__ Wt,   // [ntot][KTOT] bf16 swizzled
    const unsigned short* __restrict__ Xr,   // [rows][KTOT] bf16 swizzled
    const float* __restrict__ bias,          // [ntot]
    void* __restrict__ outp)
{
    constexpr int NT = KTOT / 64;
    __shared__ unsigned short ldsW[2][128 * 64];  // 2 x 16 KB
    __shared__ unsigned short ldsX[2][128 * 64];  // 2 x 16 KB

    int tid = threadIdx.x;
    int w = tid >> 6;
    int l = tid & 63;

    // block id -> (m-tile, n-tile); bijective XCD swizzle when NY>1
    int bid = blockIdx.x;
    if (NY > 1) {
        int cpx = gridDim.x >> 3;              // gridDim.x % 8 == 0
        bid = (bid & 7) * cpx + (bid >> 3);
    }
    int m0 = (bid / NY) * 128;
    int n0 = (bid % NY) * 128;

    int wm = w >> 1;          // 0..1
    int wn = w & 1;           // 0..1
    int r16 = l & 15;
    int kq = l >> 4;          // 0..3
    int rowmask = (r16 & 7) << 4;

    f32x4 acc[4][4] = {};

    // per-wave/lane invariant staging geometry
    int loff_row[4], loff_col[4];
    #pragma unroll
    for (int i = 0; i < 4; ++i) {
        int loff = i * 4096 + w * 1024 + l * 16;   // byte within 16 KB tile
        loff_row[i] = loff >> 7;
        loff_col[i] = loff & 127;
    }

    auto STAGE = [&](int buf, int kt) {
        #pragma unroll
        for (int i = 0; i < 4; ++i) {
            const char* g = (const char*)Wt +
                (size_t)(n0 + loff_row[i]) * (KTOT * 2) + kt * 128 + loff_col[i];
            gload16(g, (char*)&ldsW[buf][0] + i * 4096 + w * 1024);
        }
        #pragma unroll
        for (int i = 0; i < 4; ++i) {
            int gm = m0 + loff_row[i];
            if (gm > N_NODES - 1) gm = N_NODES - 1;
            const char* g = (const char*)Xr +
                (size_t)gm * (KTOT * 2) + kt * 128 + loff_col[i];
            gload16(g, (char*)&ldsX[buf][0] + i * 4096 + w * 1024);
        }
    };

    STAGE(0, 0);

    for (int kt = 0; kt < NT; ++kt) {
        int cur = kt & 1;
        if (kt + 1 < NT) {
            STAGE(cur ^ 1, kt + 1);
            asm volatile("s_waitcnt vmcnt(8)" ::: "memory");  // cur tile done
        } else {
            asm volatile("s_waitcnt vmcnt(0)" ::: "memory");
        }
        __builtin_amdgcn_s_barrier();
        asm volatile("" ::: "memory");

        const char* bW = (const char*)&ldsW[cur][0];
        const char* bX = (const char*)&ldsX[cur][0];
        __builtin_amdgcn_s_setprio(1);
        #pragma unroll
        for (int kk = 0; kk < 2; ++kk) {
            int posb = (kk * 64 + kq * 16) ^ rowmask;
            bf16x8 a[4], b[4];
            #pragma unroll
            for (int ni = 0; ni < 4; ++ni)
                a[ni] = *(const bf16x8*)(bW + (wn * 64 + ni * 16 + r16) * 128 + posb);
            #pragma unroll
            for (int mi = 0; mi < 4; ++mi)
                b[mi] = *(const bf16x8*)(bX + (wm * 64 + mi * 16 + r16) * 128 + posb);
            #pragma unroll
            for (int mi = 0; mi < 4; ++mi)
                #pragma unroll
                for (int ni = 0; ni < 4; ++ni)
                    acc[mi][ni] = __builtin_amdgcn_mfma_f32_16x16x32_bf16(
                        a[ni], b[mi], acc[mi][ni], 0, 0, 0);
        }
        __builtin_amdgcn_s_setprio(0);
        __builtin_amdgcn_s_barrier();
        asm volatile("" ::: "memory");
    }

    // ---- epilogue ----
    #pragma unroll
    for (int mi = 0; mi < 4; ++mi) {
        int m = m0 + wm * 64 + mi * 16 + r16;
        if (m >= N_NODES) continue;
        #pragma unroll
        for (int ni = 0; ni < 4; ++ni) {
            int nc = n0 + wn * 64 + ni * 16 + kq * 4;   // 4 consecutive n
            float4 bv = *(const float4*)(bias + nc);
            float x0 = acc[mi][ni][0] + bv.x;
            float x1 = acc[mi][ni][1] + bv.y;
            float x2 = acc[mi][ni][2] + bv.z;
            float x3 = acc[mi][ni][3] + bv.w;
            if (GELU_OUT) {
                const float s = 0.70710678118654752f;
                float g0 = 0.5f * x0 * (1.0f + erff(x0 * s));
                float g1 = 0.5f * x1 * (1.0f + erff(x1 * s));
                float g2 = 0.5f * x2 * (1.0f + erff(x2 * s));
                float g3 = 0.5f * x3 * (1.0f + erff(x3 * s));
                ushort4 p;
                p.x = f32_to_bf16(g0); p.y = f32_to_bf16(g1);
                p.z = f32_to_bf16(g2); p.w = f32_to_bf16(g3);
                unsigned short* row = (unsigned short*)outp + (size_t)m * HID;
                int byteoff = (nc * 2) ^ ((m & 7) << 4);   // swizzled hdn
                *(ushort4*)((char*)row + byteoff) = p;
            } else {
                float4 o = make_float4(x0, x1, x2, x3);
                *(float4*)((float*)outp + (size_t)m * DIM + nc) = o;
            }
        }
    }
}

// ---------------------------------------------------------------------------
extern "C" void kernel_launch(void* const* d_in, const int* in_sizes, int n_in,
                              void* d_out, int out_size, void* d_ws, size_t ws_size,
                              hipStream_t stream) {
    const float* h  = (const float*)d_in[0];
    const int*   ei = (const int*)d_in[1];
    const float* W1 = (const float*)d_in[2];
    const float* b1 = (const float*)d_in[3];
    const float* W2 = (const float*)d_in[4];
    const float* b2 = (const float*)d_in[5];
    float* out = (float*)d_out;

    // workspace layout
    unsigned short* X   = (unsigned short*)d_ws;             // MROWS_PAD*256 bf16
    unsigned short* hdn = X + (size_t)MROWS_PAD * 256;       // MROWS_PAD*512 bf16
    unsigned short* W1T = hdn + (size_t)MROWS_PAD * 512;     // 512*256 bf16
    unsigned short* W2T = W1T + 512 * 256;                   // 128*512 bf16
    int* cnt = (int*)(W2T + 128 * 512);                      // N (also cursor)
    int* row_start = cnt + N_NODES;                          // N+1
    int* bsum = row_start + N_NODES + 1;                     // 128
    int* csr = bsum + 128;                                   // E

    // prep (independent of CSR)
    mgl_transpose_w1_kernel<<<512, 256, 0, stream>>>(W1, W1T);
    mgl_transpose_w2_kernel<<<128, 256, 0, stream>>>(W2, W2T);
    mgl_convert_h_kernel<<<(N_NODES * 32 + 255) / 256, 256, 0, stream>>>(h, X);

    // CSR build
    hipMemsetAsync(cnt, 0, N_NODES * sizeof(int), stream);
    mgl_count_kernel<<<(EDGES + 255) / 256, 256, 0, stream>>>(ei, cnt);
    mgl_scan_block_kernel<<<SCAN_NBLK, 256, 0, stream>>>(cnt, row_start, bsum);
    mgl_scan_bsum_kernel<<<1, 128, 0, stream>>>(bsum);
    mgl_scan_add_kernel<<<(N_NODES + 255) / 256, 256, 0, stream>>>(row_start, bsum);
    hipMemsetAsync(cnt, 0, N_NODES * sizeof(int), stream);  // reuse as cursor
    mgl_fill_kernel<<<(EDGES + 255) / 256, 256, 0, stream>>>(ei, row_start, cnt, csr);
    // gather reads bf16 X[:,0:128] (written by convert) -> must follow convert
    mgl_gather_mean_kernel<<<(N_NODES + 3) / 4, 256, 0, stream>>>(X, row_start, csr, X);

    // MLP via MFMA
    int mtiles = MROWS_PAD / 128;  // 782
    mgl_gemm_kernel<256, 4, true><<<mtiles * 4, 256, 0, stream>>>(W1T, X, b1, hdn);
    mgl_gemm_kernel<512, 1, false><<<mtiles, 256, 0, stream>>>(W2T, hdn, b2, out);
}

// Round 5
// 249.224 us; speedup vs baseline: 6.8164x; 1.0532x over previous
//
#include <hip/hip_runtime.h>
#include <hip/hip_bf16.h>
#include <math.h>

#define N_NODES 100000
#define DIM 128
#define HID 512
#define EDGES 600000
#define SCAN_CHUNK 1024
#define SCAN_NBLK ((N_NODES + SCAN_CHUNK - 1) / SCAN_CHUNK)  // 98
#define MROWS_PAD 100096   // 782 * 128

typedef short bf16x8 __attribute__((ext_vector_type(8)));
typedef float f32x4 __attribute__((ext_vector_type(4)));

// Swizzle convention (rule #21 both-sides): for every bf16 staging buffer
// (X, W1T, W2T, hdn), physical byte offset within a row = logical byte
// offset XOR ((row & 7) << 4). global_load_lds stages rows linearly, the
// MFMA fragment ds_read applies the same XOR -> conflict-free LDS banks.

__device__ inline unsigned short f32_to_bf16(float f) {
    unsigned int u = __float_as_uint(f);
    u += 0x7fff + ((u >> 16) & 1);
    return (unsigned short)(u >> 16);
}

// fast exact-enough GELU: tanh form via hw exp2 + rcp (~8 VALU ops).
// |gelu_tanh - gelu_erf| <= ~5e-4 absolute.
__device__ inline float gelu_f(float x) {
    float x3 = x * x * x;
    float y = 0.7978845608028654f * x + 0.0356774081f * x3;   // sqrt(2/pi)*(x+0.044715x^3)
    float e = exp2f(y * 2.8853900817779268f);                 // exp(2y)
    float t = 1.0f - 2.0f * __builtin_amdgcn_rcpf(e + 1.0f);  // tanh(y)
    return 0.5f * x * (1.0f + t);
}

__device__ inline void gload16(const void* g, void* l) {
    __builtin_amdgcn_global_load_lds(
        (const __attribute__((address_space(1))) unsigned int*)g,
        (__attribute__((address_space(3))) unsigned int*)l,
        16, 0, 0);
}

// ---------------------------------------------------------------------------
// CSR build: count, scan, fill
// ---------------------------------------------------------------------------
__global__ __launch_bounds__(256) void mgl_count_kernel(
    const int* __restrict__ ei, int* __restrict__ cnt)
{
    int e = blockIdx.x * 256 + threadIdx.x;
    if (e < EDGES) atomicAdd(&cnt[ei[EDGES + e]], 1);
}

__global__ __launch_bounds__(256) void mgl_scan_block_kernel(
    const int* __restrict__ cnt, int* __restrict__ row_start, int* __restrict__ bsum)
{
    __shared__ int sdata[256];
    int t = threadIdx.x;
    int base = blockIdx.x * SCAN_CHUNK + t * 4;
    int v[4];
    #pragma unroll
    for (int i = 0; i < 4; ++i) {
        int idx = base + i;
        v[i] = (idx < N_NODES) ? cnt[idx] : 0;
    }
    int tsum = v[0] + v[1] + v[2] + v[3];
    sdata[t] = tsum;
    __syncthreads();
    for (int off = 1; off < 256; off <<= 1) {
        int x = (t >= off) ? sdata[t - off] : 0;
        __syncthreads();
        sdata[t] += x;
        __syncthreads();
    }
    int run = (t > 0) ? sdata[t - 1] : 0;
    #pragma unroll
    for (int i = 0; i < 4; ++i) {
        int idx = base + i;
        if (idx < N_NODES) row_start[idx] = run;
        run += v[i];
    }
    if (t == 255) bsum[blockIdx.x] = sdata[255];
}

__global__ __launch_bounds__(128) void mgl_scan_bsum_kernel(int* __restrict__ bsum)
{
    __shared__ int sd[128];
    int t = threadIdx.x;
    int v = (t < SCAN_NBLK) ? bsum[t] : 0;
    sd[t] = v;
    __syncthreads();
    for (int off = 1; off < 128; off <<= 1) {
        int x = (t >= off) ? sd[t - off] : 0;
        __syncthreads();
        sd[t] += x;
        __syncthreads();
    }
    if (t < SCAN_NBLK) bsum[t] = sd[t] - v;  // exclusive
}

__global__ __launch_bounds__(256) void mgl_scan_add_kernel(
    int* __restrict__ row_start, const int* __restrict__ bsum)
{
    int i = blockIdx.x * 256 + threadIdx.x;
    if (i < N_NODES) row_start[i] += bsum[i / SCAN_CHUNK];
    if (i == 0) row_start[N_NODES] = EDGES;
}

__global__ __launch_bounds__(256) void mgl_fill_kernel(
    const int* __restrict__ ei, const int* __restrict__ row_start,
    int* __restrict__ cursor, int* __restrict__ csr)
{
    int e = blockIdx.x * 256 + threadIdx.x;
    if (e >= EDGES) return;
    int s = ei[e];
    int t = ei[EDGES + e];
    int pos = atomicAdd(&cursor[t], 1);
    csr[row_start[t] + pos] = s;
}

// ---------------------------------------------------------------------------
// h -> bf16 into X[:, 0:128]  (swizzled layout)
// ---------------------------------------------------------------------------
__global__ __launch_bounds__(256) void mgl_convert_h_kernel(
    const float* __restrict__ h, unsigned short* __restrict__ X)
{
    int t = blockIdx.x * 256 + threadIdx.x;
    if (t >= N_NODES * (DIM / 4)) return;
    int node = t >> 5;          // 32 float4 per node
    int c4 = t & 31;
    float4 v = *(const float4*)(h + (size_t)node * DIM + c4 * 4);
    ushort4 p;
    p.x = f32_to_bf16(v.x); p.y = f32_to_bf16(v.y);
    p.z = f32_to_bf16(v.z); p.w = f32_to_bf16(v.w);
    int byteoff = (c4 * 8) ^ ((node & 7) << 4);
    *(ushort4*)((char*)(X + (size_t)node * 256) + byteoff) = p;
}

// ---------------------------------------------------------------------------
// Gather-mean (one wave/node), reads bf16 X[:,0:128], writes bf16 X[:,128:256]
// ---------------------------------------------------------------------------
__global__ __launch_bounds__(256) void mgl_gather_mean_kernel(
    const unsigned short* __restrict__ Xb, const int* __restrict__ row_start,
    const int* __restrict__ csr, unsigned short* __restrict__ X)
{
    int v = blockIdx.x * 4 + (threadIdx.x >> 6);
    if (v >= N_NODES) return;
    int lane = threadIdx.x & 63;
    int beg = row_start[v];
    int end = row_start[v + 1];
    int laneByte = lane * 4;              // logical byte of elements {2*lane, 2*lane+1}
    const char* xb = (const char*)Xb;

    if (end > beg) {
        float2 acc = make_float2(0.f, 0.f);
        for (int i = beg; i < end; ++i) {
            int s = csr[i];  // wave-uniform
            unsigned int pk = *(const unsigned int*)(
                xb + (size_t)s * 512 + (laneByte ^ ((s & 7) << 4)));
            acc.x += __uint_as_float(pk << 16);
            acc.y += __uint_as_float(pk & 0xffff0000u);
        }
        float inv = 1.f / (float)(end - beg);
        unsigned int po = (unsigned int)f32_to_bf16(acc.x * inv) |
                          ((unsigned int)f32_to_bf16(acc.y * inv) << 16);
        *(unsigned int*)((char*)(X + (size_t)v * 256) +
                         ((256 + laneByte) ^ ((v & 7) << 4))) = po;
    } else {
        // isolated node: copy own bf16 row
        unsigned int pk = *(const unsigned int*)(
            xb + (size_t)v * 512 + (laneByte ^ ((v & 7) << 4)));
        *(unsigned int*)((char*)(X + (size_t)v * 256) +
                         ((256 + laneByte) ^ ((v & 7) << 4))) = pk;
    }
}

// ---------------------------------------------------------------------------
// Weight transposes -> bf16 [out][in], swizzled
// ---------------------------------------------------------------------------
__global__ __launch_bounds__(256) void mgl_transpose_w1_kernel(
    const float* __restrict__ W1, unsigned short* __restrict__ W1T)
{
    int n = blockIdx.x;            // 0..511
    int k = threadIdx.x;           // 0..255
    unsigned short val = f32_to_bf16(W1[(size_t)k * HID + n]);
    int byteoff = (k * 2) ^ ((n & 7) << 4);
    *(unsigned short*)((char*)(W1T + (size_t)n * 256) + byteoff) = val;
}

__global__ __launch_bounds__(256) void mgl_transpose_w2_kernel(
    const float* __restrict__ W2, unsigned short* __restrict__ W2T)
{
    int n = blockIdx.x;            // 0..127
    #pragma unroll
    for (int it = 0; it < 2; ++it) {
        int k = threadIdx.x + it * 256;  // 0..511
        unsigned short val = f32_to_bf16(W2[(size_t)k * DIM + n]);
        int byteoff = (k * 2) ^ ((n & 7) << 4);
        *(unsigned short*)((char*)(W2T + (size_t)n * 512) + byteoff) = val;
    }
}

// ---------------------------------------------------------------------------
// MFMA GEMM: out[m][n] = f( sum_k Xr[m][k] * Wt[n][k] + bias[n] )
// 128x128 tile, BK=64, 4 waves, m97 structure: SINGLE-buffered 32 KB LDS
// (5 blocks/CU -> inter-block latency hiding), 2 barriers per K-step,
// XOR-swizzled LDS via pre-swizzled global layout.
// ---------------------------------------------------------------------------
template<int KTOT, int NY, bool GELU_OUT>
__global__ __launch_bounds__(256) void mgl_gemm_kernel(
    const unsigned short* __restrict__ Wt,   // [ntot][KTOT] bf16 swizzled
    const unsigned short* __restrict__ Xr,   // [rows][KTOT] bf16 swizzled
    const float* __restrict__ bias,          // [ntot]
    void* __restrict__ outp)
{
    constexpr int NT = KTOT / 64;
    __shared__ unsigned short ldsW[128 * 64];  // 16 KB
    __shared__ unsigned short ldsX[128 * 64];  // 16 KB

    int tid = threadIdx.x;
    int w = tid >> 6;
    int l = tid & 63;

    // block id -> (m-tile, n-tile); bijective XCD swizzle when NY>1
    int bid = blockIdx.x;
    if (NY > 1) {
        int cpx = gridDim.x >> 3;              // gridDim.x % 8 == 0
        bid = (bid & 7) * cpx + (bid >> 3);
    }
    int m0 = (bid / NY) * 128;
    int n0 = (bid % NY) * 128;

    int wm = w >> 1;          // 0..1
    int wn = w & 1;           // 0..1
    int r16 = l & 15;
    int kq = l >> 4;          // 0..3
    int rowmask = (r16 & 7) << 4;

    f32x4 acc[4][4] = {};

    // per-wave/lane invariant staging geometry
    int loff_row[4], loff_col[4];
    #pragma unroll
    for (int i = 0; i < 4; ++i) {
        int loff = i * 4096 + w * 1024 + l * 16;   // byte within 16 KB tile
        loff_row[i] = loff >> 7;
        loff_col[i] = loff & 127;
    }

    for (int kt = 0; kt < NT; ++kt) {
        // ---- stage both tiles (8 global_load_lds / wave) ----
        #pragma unroll
        for (int i = 0; i < 4; ++i) {
            const char* g = (const char*)Wt +
                (size_t)(n0 + loff_row[i]) * (KTOT * 2) + kt * 128 + loff_col[i];
            gload16(g, (char*)ldsW + i * 4096 + w * 1024);
        }
        #pragma unroll
        for (int i = 0; i < 4; ++i) {
            int gm = m0 + loff_row[i];
            if (gm > N_NODES - 1) gm = N_NODES - 1;
            const char* g = (const char*)Xr +
                (size_t)gm * (KTOT * 2) + kt * 128 + loff_col[i];
            gload16(g, (char*)ldsX + i * 4096 + w * 1024);
        }
        __syncthreads();   // drains vmcnt -> LDS visible

        #pragma unroll
        for (int kk = 0; kk < 2; ++kk) {
            int posb = (kk * 64 + kq * 16) ^ rowmask;
            bf16x8 a[4], b[4];
            #pragma unroll
            for (int ni = 0; ni < 4; ++ni)
                a[ni] = *(const bf16x8*)((const char*)ldsW +
                          (wn * 64 + ni * 16 + r16) * 128 + posb);
            #pragma unroll
            for (int mi = 0; mi < 4; ++mi)
                b[mi] = *(const bf16x8*)((const char*)ldsX +
                          (wm * 64 + mi * 16 + r16) * 128 + posb);
            #pragma unroll
            for (int mi = 0; mi < 4; ++mi)
                #pragma unroll
                for (int ni = 0; ni < 4; ++ni)
                    acc[mi][ni] = __builtin_amdgcn_mfma_f32_16x16x32_bf16(
                        a[ni], b[mi], acc[mi][ni], 0, 0, 0);
        }
        __syncthreads();   // reads done before next stage overwrites
    }

    // ---- epilogue ----
    #pragma unroll
    for (int mi = 0; mi < 4; ++mi) {
        int m = m0 + wm * 64 + mi * 16 + r16;
        if (m >= N_NODES) continue;
        #pragma unroll
        for (int ni = 0; ni < 4; ++ni) {
            int nc = n0 + wn * 64 + ni * 16 + kq * 4;   // 4 consecutive n
            float4 bv = *(const float4*)(bias + nc);
            float x0 = acc[mi][ni][0] + bv.x;
            float x1 = acc[mi][ni][1] + bv.y;
            float x2 = acc[mi][ni][2] + bv.z;
            float x3 = acc[mi][ni][3] + bv.w;
            if (GELU_OUT) {
                ushort4 p;
                p.x = f32_to_bf16(gelu_f(x0));
                p.y = f32_to_bf16(gelu_f(x1));
                p.z = f32_to_bf16(gelu_f(x2));
                p.w = f32_to_bf16(gelu_f(x3));
                unsigned short* row = (unsigned short*)outp + (size_t)m * HID;
                int byteoff = (nc * 2) ^ ((m & 7) << 4);   // swizzled hdn
                *(ushort4*)((char*)row + byteoff) = p;
            } else {
                float4 o = make_float4(x0, x1, x2, x3);
                *(float4*)((float*)outp + (size_t)m * DIM + nc) = o;
            }
        }
    }
}

// ---------------------------------------------------------------------------
extern "C" void kernel_launch(void* const* d_in, const int* in_sizes, int n_in,
                              void* d_out, int out_size, void* d_ws, size_t ws_size,
                              hipStream_t stream) {
    const float* h  = (const float*)d_in[0];
    const int*   ei = (const int*)d_in[1];
    const float* W1 = (const float*)d_in[2];
    const float* b1 = (const float*)d_in[3];
    const float* W2 = (const float*)d_in[4];
    const float* b2 = (const float*)d_in[5];
    float* out = (float*)d_out;

    // workspace layout
    unsigned short* X   = (unsigned short*)d_ws;             // MROWS_PAD*256 bf16
    unsigned short* hdn = X + (size_t)MROWS_PAD * 256;       // MROWS_PAD*512 bf16
    unsigned short* W1T = hdn + (size_t)MROWS_PAD * 512;     // 512*256 bf16
    unsigned short* W2T = W1T + 512 * 256;                   // 128*512 bf16
    int* cnt = (int*)(W2T + 128 * 512);                      // N (also cursor)
    int* row_start = cnt + N_NODES;                          // N+1
    int* bsum = row_start + N_NODES + 1;                     // 128
    int* csr = bsum + 128;                                   // E

    // prep (independent of CSR)
    mgl_transpose_w1_kernel<<<512, 256, 0, stream>>>(W1, W1T);
    mgl_transpose_w2_kernel<<<128, 256, 0, stream>>>(W2, W2T);
    mgl_convert_h_kernel<<<(N_NODES * 32 + 255) / 256, 256, 0, stream>>>(h, X);

    // CSR build
    hipMemsetAsync(cnt, 0, N_NODES * sizeof(int), stream);
    mgl_count_kernel<<<(EDGES + 255) / 256, 256, 0, stream>>>(ei, cnt);
    mgl_scan_block_kernel<<<SCAN_NBLK, 256, 0, stream>>>(cnt, row_start, bsum);
    mgl_scan_bsum_kernel<<<1, 128, 0, stream>>>(bsum);
    mgl_scan_add_kernel<<<(N_NODES + 255) / 256, 256, 0, stream>>>(row_start, bsum);
    hipMemsetAsync(cnt, 0, N_NODES * sizeof(int), stream);  // reuse as cursor
    mgl_fill_kernel<<<(EDGES + 255) / 256, 256, 0, stream>>>(ei, row_start, cnt, csr);
    // gather reads bf16 X[:,0:128] (written by convert) -> must follow convert
    mgl_gather_mean_kernel<<<(N_NODES + 3) / 4, 256, 0, stream>>>(X, row_start, csr, X);

    // MLP via MFMA
    int mtiles = MROWS_PAD / 128;  // 782
    mgl_gemm_kernel<256, 4, true><<<mtiles * 4, 256, 0, stream>>>(W1T, X, b1, hdn);
    mgl_gemm_kernel<512, 1, false><<<mtiles, 256, 0, stream>>>(W2T, hdn, b2, out);
}

// Round 6
// 221.716 us; speedup vs baseline: 7.6621x; 1.1241x over previous
//
#include <hip/hip_runtime.h>
#include <hip/hip_bf16.h>
#include <math.h>

#define N_NODES 100000
#define DIM 128
#define HID 512
#define EDGES 600000
#define SCAN_CHUNK 1024
#define SCAN_NBLK ((N_NODES + SCAN_CHUNK - 1) / SCAN_CHUNK)  // 98
#define MROWS_PAD 100096   // 391 * 256

typedef short bf16x8 __attribute__((ext_vector_type(8)));
typedef float f32x4 __attribute__((ext_vector_type(4)));

// Swizzle convention (rule #21 both-sides): for every bf16 staging buffer
// (X, W1T, W2T, hdn), physical byte offset within a row = logical byte
// offset XOR ((row & 7) << 4). global_load_lds stages 128-B row-chunks
// linearly, the MFMA fragment ds_read applies the same XOR -> LDS banks
// conflict-free. XOR touches bits 4..6 only, so every 128-B chunk is
// internally permuted and chunk boundaries are preserved.

__device__ inline unsigned short f32_to_bf16(float f) {
    unsigned int u = __float_as_uint(f);
    u += 0x7fff + ((u >> 16) & 1);
    return (unsigned short)(u >> 16);
}

// fast GELU: tanh form via hw exp2 + rcp. |gelu_tanh - gelu_erf| <= ~5e-4.
__device__ inline float gelu_f(float x) {
    float x3 = x * x * x;
    float y = 0.7978845608028654f * x + 0.0356774081f * x3;
    float e = exp2f(y * 2.8853900817779268f);                 // exp(2y)
    float t = 1.0f - 2.0f * __builtin_amdgcn_rcpf(e + 1.0f);  // tanh(y)
    return 0.5f * x * (1.0f + t);
}

__device__ inline void gload16(const void* g, void* l) {
    __builtin_amdgcn_global_load_lds(
        (const __attribute__((address_space(1))) unsigned int*)g,
        (__attribute__((address_space(3))) unsigned int*)l,
        16, 0, 0);
}

// ---------------------------------------------------------------------------
// Fused prep kernel: W1 transpose | W2 transpose | h->bf16 convert | dst count
// block ranges select the role (all independent, all read-only inputs).
// ---------------------------------------------------------------------------
#define PREP_W1_BLKS 512
#define PREP_W2_BLKS 128
#define PREP_CONV_BLKS 12500                  // N_NODES*32/256
#define PREP_COUNT_BLKS ((EDGES + 255) / 256) // 2344
#define PREP_TOTAL (PREP_W1_BLKS + PREP_W2_BLKS + PREP_CONV_BLKS + PREP_COUNT_BLKS)

__global__ __launch_bounds__(256) void mgl_prep_kernel(
    const float* __restrict__ h, const int* __restrict__ ei,
    const float* __restrict__ W1, const float* __restrict__ W2,
    unsigned short* __restrict__ X, unsigned short* __restrict__ W1T,
    unsigned short* __restrict__ W2T, int* __restrict__ cnt)
{
    int b = blockIdx.x;
    if (b < PREP_W1_BLKS) {
        int n = b;                       // 0..511
        int k = threadIdx.x;             // 0..255
        unsigned short val = f32_to_bf16(W1[(size_t)k * HID + n]);
        int byteoff = (k * 2) ^ ((n & 7) << 4);
        *(unsigned short*)((char*)(W1T + (size_t)n * 256) + byteoff) = val;
        return;
    }
    b -= PREP_W1_BLKS;
    if (b < PREP_W2_BLKS) {
        int n = b;                       // 0..127
        #pragma unroll
        for (int it = 0; it < 2; ++it) {
            int k = threadIdx.x + it * 256;  // 0..511
            unsigned short val = f32_to_bf16(W2[(size_t)k * DIM + n]);
            int byteoff = (k * 2) ^ ((n & 7) << 4);
            *(unsigned short*)((char*)(W2T + (size_t)n * 512) + byteoff) = val;
        }
        return;
    }
    b -= PREP_W2_BLKS;
    if (b < PREP_CONV_BLKS) {
        int t = b * 256 + threadIdx.x;
        if (t >= N_NODES * (DIM / 4)) return;
        int node = t >> 5;               // 32 float4 per node
        int c4 = t & 31;
        float4 v = *(const float4*)(h + (size_t)node * DIM + c4 * 4);
        ushort4 p;
        p.x = f32_to_bf16(v.x); p.y = f32_to_bf16(v.y);
        p.z = f32_to_bf16(v.z); p.w = f32_to_bf16(v.w);
        int byteoff = (c4 * 8) ^ ((node & 7) << 4);
        *(ushort4*)((char*)(X + (size_t)node * 256) + byteoff) = p;
        return;
    }
    b -= PREP_CONV_BLKS;
    {
        int e = b * 256 + threadIdx.x;
        if (e < EDGES) atomicAdd(&cnt[ei[EDGES + e]], 1);
    }
}

// ---------------------------------------------------------------------------
// Scan (3 kernels)
// ---------------------------------------------------------------------------
__global__ __launch_bounds__(256) void mgl_scan_block_kernel(
    const int* __restrict__ cnt, int* __restrict__ row_start, int* __restrict__ bsum)
{
    __shared__ int sdata[256];
    int t = threadIdx.x;
    int base = blockIdx.x * SCAN_CHUNK + t * 4;
    int v[4];
    #pragma unroll
    for (int i = 0; i < 4; ++i) {
        int idx = base + i;
        v[i] = (idx < N_NODES) ? cnt[idx] : 0;
    }
    int tsum = v[0] + v[1] + v[2] + v[3];
    sdata[t] = tsum;
    __syncthreads();
    for (int off = 1; off < 256; off <<= 1) {
        int x = (t >= off) ? sdata[t - off] : 0;
        __syncthreads();
        sdata[t] += x;
        __syncthreads();
    }
    int run = (t > 0) ? sdata[t - 1] : 0;
    #pragma unroll
    for (int i = 0; i < 4; ++i) {
        int idx = base + i;
        if (idx < N_NODES) row_start[idx] = run;
        run += v[i];
    }
    if (t == 255) bsum[blockIdx.x] = sdata[255];
}

__global__ __launch_bounds__(128) void mgl_scan_bsum_kernel(int* __restrict__ bsum)
{
    __shared__ int sd[128];
    int t = threadIdx.x;
    int v = (t < SCAN_NBLK) ? bsum[t] : 0;
    sd[t] = v;
    __syncthreads();
    for (int off = 1; off < 128; off <<= 1) {
        int x = (t >= off) ? sd[t - off] : 0;
        __syncthreads();
        sd[t] += x;
        __syncthreads();
    }
    if (t < SCAN_NBLK) bsum[t] = sd[t] - v;  // exclusive
}

__global__ __launch_bounds__(256) void mgl_scan_add_kernel(
    int* __restrict__ row_start, const int* __restrict__ bsum)
{
    int i = blockIdx.x * 256 + threadIdx.x;
    if (i < N_NODES) row_start[i] += bsum[i / SCAN_CHUNK];
    if (i == 0) row_start[N_NODES] = EDGES;
}

// ---------------------------------------------------------------------------
// Fill: consume leftover counts with atomicSub (no cursor memset needed).
// cnt ends at 0 for every node -> deterministic across graph replays
// (prep re-counts after the single memset each replay).
// ---------------------------------------------------------------------------
__global__ __launch_bounds__(256) void mgl_fill_kernel(
    const int* __restrict__ ei, const int* __restrict__ row_start,
    int* __restrict__ cnt, int* __restrict__ csr)
{
    int e = blockIdx.x * 256 + threadIdx.x;
    if (e >= EDGES) return;
    int s = ei[e];
    int t = ei[EDGES + e];
    int pos = atomicSub(&cnt[t], 1) - 1;
    csr[row_start[t] + pos] = s;
}

// ---------------------------------------------------------------------------
// Gather-mean (one wave/node): neighbor ids loaded 64-wide then shfl-broadcast
// (removes serial csr-load dependency). Reads bf16 X[:,0:128], writes bf16
// X[:,128:256].
// ---------------------------------------------------------------------------
__global__ __launch_bounds__(256) void mgl_gather_mean_kernel(
    const unsigned short* __restrict__ Xb, const int* __restrict__ row_start,
    const int* __restrict__ csr, unsigned short* __restrict__ X)
{
    int v = blockIdx.x * 4 + (threadIdx.x >> 6);
    if (v >= N_NODES) return;
    int lane = threadIdx.x & 63;
    int beg = row_start[v];
    int nb = row_start[v + 1] - beg;
    int laneByte = lane * 4;              // logical byte of elems {2lane, 2lane+1}
    const char* xb = (const char*)Xb;

    if (nb > 0) {
        float2 acc = make_float2(0.f, 0.f);
        for (int base = 0; base < nb; base += 64) {
            int rem = nb - base; if (rem > 64) rem = 64;
            int sv = (lane < rem) ? csr[beg + base + lane] : 0;
            for (int j = 0; j < rem; ++j) {
                int s = __shfl(sv, j);
                unsigned int pk = *(const unsigned int*)(
                    xb + (size_t)s * 512 + (laneByte ^ ((s & 7) << 4)));
                acc.x += __uint_as_float(pk << 16);
                acc.y += __uint_as_float(pk & 0xffff0000u);
            }
        }
        float inv = 1.f / (float)nb;
        unsigned int po = (unsigned int)f32_to_bf16(acc.x * inv) |
                          ((unsigned int)f32_to_bf16(acc.y * inv) << 16);
        *(unsigned int*)((char*)(X + (size_t)v * 256) +
                         ((256 + laneByte) ^ ((v & 7) << 4))) = po;
    } else {
        unsigned int pk = *(const unsigned int*)(
            xb + (size_t)v * 512 + (laneByte ^ ((v & 7) << 4)));
        *(unsigned int*)((char*)(X + (size_t)v * 256) +
                         ((256 + laneByte) ^ ((v & 7) << 4))) = pk;
    }
}

// ---------------------------------------------------------------------------
// MFMA GEMM: out[m][n] = f( sum_k Xr[m][k] * Wt[n][k] + bias[n] )
// 256m x 128n tile, BK=64, 8 waves (512 thr) as 4m x 2n of 64x64 wave-tiles.
// Single-buffered 48 KB LDS (W 16 KB + X 32 KB), 2 barriers/K-step,
// XOR-swizzled LDS via pre-swizzled global layout. 6 gload16/thread/K-step.
// ---------------------------------------------------------------------------
template<int KTOT, int NY, bool GELU_OUT>
__global__ __launch_bounds__(512) void mgl_gemm_kernel(
    const unsigned short* __restrict__ Wt,   // [ntot][KTOT] bf16 swizzled
    const unsigned short* __restrict__ Xr,   // [rows][KTOT] bf16 swizzled
    const float* __restrict__ bias,          // [ntot]
    void* __restrict__ outp)
{
    constexpr int NT = KTOT / 64;
    __shared__ unsigned short ldsW[128 * 64];  // 16 KB [n][k]
    __shared__ unsigned short ldsX[256 * 64];  // 32 KB [m][k]

    int tid = threadIdx.x;
    int w = tid >> 6;         // 0..7
    int l = tid & 63;

    // block id -> (m-tile, n-tile); bijective XCD swizzle (m204) when NY>1
    int bid = blockIdx.x;
    if (NY > 1) {
        int nwg = gridDim.x;
        int q = nwg >> 3, r = nwg & 7;
        int xcd = bid & 7, idx = bid >> 3;
        bid = (xcd < r ? xcd * (q + 1) : r * (q + 1) + (xcd - r) * q) + idx;
    }
    int m0 = (bid / NY) * 256;
    int n0 = (bid % NY) * 128;

    int wm = w >> 1;          // 0..3
    int wn = w & 1;           // 0..1
    int r16 = l & 15;
    int kq = l >> 4;          // 0..3
    int rowmask = (r16 & 7) << 4;

    f32x4 acc[4][4] = {};

    // staging geometry: thread covers 16 B at tile byte off = i*8192 + tid*16
    int srow = tid >> 3;            // row within 64-row group
    int scol = (tid & 7) << 4;      // byte col within 128-B row

    for (int kt = 0; kt < NT; ++kt) {
        // ---- stage W tile (128n x 64k = 16 KB, 2 passes) ----
        #pragma unroll
        for (int i = 0; i < 2; ++i) {
            int row = i * 64 + srow;
            const char* g = (const char*)Wt +
                (size_t)(n0 + row) * (KTOT * 2) + kt * 128 + scol;
            gload16(g, (char*)ldsW + i * 8192 + tid * 16);
        }
        // ---- stage X tile (256m x 64k = 32 KB, 4 passes), clamp tail ----
        #pragma unroll
        for (int i = 0; i < 4; ++i) {
            int gm = m0 + i * 64 + srow;
            if (gm > N_NODES - 1) gm = N_NODES - 1;
            const char* g = (const char*)Xr +
                (size_t)gm * (KTOT * 2) + kt * 128 + scol;
            gload16(g, (char*)ldsX + i * 8192 + tid * 16);
        }
        __syncthreads();   // drains vmcnt -> LDS visible

        #pragma unroll
        for (int kk = 0; kk < 2; ++kk) {
            int posb = (kk * 64 + kq * 16) ^ rowmask;
            bf16x8 a[4], b[4];
            #pragma unroll
            for (int ni = 0; ni < 4; ++ni)
                a[ni] = *(const bf16x8*)((const char*)ldsW +
                          (wn * 64 + ni * 16 + r16) * 128 + posb);
            #pragma unroll
            for (int mi = 0; mi < 4; ++mi)
                b[mi] = *(const bf16x8*)((const char*)ldsX +
                          (wm * 64 + mi * 16 + r16) * 128 + posb);
            #pragma unroll
            for (int mi = 0; mi < 4; ++mi)
                #pragma unroll
                for (int ni = 0; ni < 4; ++ni)
                    acc[mi][ni] = __builtin_amdgcn_mfma_f32_16x16x32_bf16(
                        a[ni], b[mi], acc[mi][ni], 0, 0, 0);
        }
        __syncthreads();   // reads done before next stage overwrites
    }

    // ---- epilogue ----
    #pragma unroll
    for (int mi = 0; mi < 4; ++mi) {
        int m = m0 + wm * 64 + mi * 16 + r16;
        if (m >= N_NODES) continue;
        #pragma unroll
        for (int ni = 0; ni < 4; ++ni) {
            int nc = n0 + wn * 64 + ni * 16 + kq * 4;   // 4 consecutive n
            float4 bv = *(const float4*)(bias + nc);
            float x0 = acc[mi][ni][0] + bv.x;
            float x1 = acc[mi][ni][1] + bv.y;
            float x2 = acc[mi][ni][2] + bv.z;
            float x3 = acc[mi][ni][3] + bv.w;
            if (GELU_OUT) {
                ushort4 p;
                p.x = f32_to_bf16(gelu_f(x0));
                p.y = f32_to_bf16(gelu_f(x1));
                p.z = f32_to_bf16(gelu_f(x2));
                p.w = f32_to_bf16(gelu_f(x3));
                unsigned short* row = (unsigned short*)outp + (size_t)m * HID;
                int byteoff = (nc * 2) ^ ((m & 7) << 4);   // swizzled hdn
                *(ushort4*)((char*)row + byteoff) = p;
            } else {
                float4 o = make_float4(x0, x1, x2, x3);
                *(float4*)((float*)outp + (size_t)m * DIM + nc) = o;
            }
        }
    }
}

// ---------------------------------------------------------------------------
extern "C" void kernel_launch(void* const* d_in, const int* in_sizes, int n_in,
                              void* d_out, int out_size, void* d_ws, size_t ws_size,
                              hipStream_t stream) {
    const float* h  = (const float*)d_in[0];
    const int*   ei = (const int*)d_in[1];
    const float* W1 = (const float*)d_in[2];
    const float* b1 = (const float*)d_in[3];
    const float* W2 = (const float*)d_in[4];
    const float* b2 = (const float*)d_in[5];
    float* out = (float*)d_out;

    // workspace layout
    unsigned short* X   = (unsigned short*)d_ws;             // MROWS_PAD*256 bf16
    unsigned short* hdn = X + (size_t)MROWS_PAD * 256;       // MROWS_PAD*512 bf16
    unsigned short* W1T = hdn + (size_t)MROWS_PAD * 512;     // 512*256 bf16
    unsigned short* W2T = W1T + 512 * 256;                   // 128*512 bf16
    int* cnt = (int*)(W2T + 128 * 512);                      // N
    int* row_start = cnt + N_NODES;                          // N+1
    int* bsum = row_start + N_NODES + 1;                     // 128
    int* csr = bsum + 128;                                   // E

    hipMemsetAsync(cnt, 0, N_NODES * sizeof(int), stream);
    mgl_prep_kernel<<<PREP_TOTAL, 256, 0, stream>>>(h, ei, W1, W2, X, W1T, W2T, cnt);
    mgl_scan_block_kernel<<<SCAN_NBLK, 256, 0, stream>>>(cnt, row_start, bsum);
    mgl_scan_bsum_kernel<<<1, 128, 0, stream>>>(bsum);
    mgl_scan_add_kernel<<<(N_NODES + 255) / 256, 256, 0, stream>>>(row_start, bsum);
    mgl_fill_kernel<<<(EDGES + 255) / 256, 256, 0, stream>>>(ei, row_start, cnt, csr);
    mgl_gather_mean_kernel<<<(N_NODES + 3) / 4, 256, 0, stream>>>(X, row_start, csr, X);

    // MLP via MFMA: 256-row m-tiles
    int mtiles = MROWS_PAD / 256;  // 391
    mgl_gemm_kernel<256, 4, true><<<mtiles * 4, 512, 0, stream>>>(W1T, X, b1, hdn);
    mgl_gemm_kernel<512, 1, false><<<mtiles, 512, 0, stream>>>(W2T, hdn, b2, out);
}